// Round 14
// baseline (12.800 us; speedup 1.0000x reference)
//
#include <hip/hip_runtime.h>
#include <math.h>

// NUFFT type-2 exact NUDFT via MFMA, LDS-resident B.
// R14 = R13 (verified, 12.69us) + XCD-aware blockIdx swizzle (T1):
//   swz = (bid%8)*64 + bid/8  (bijective, 512 blocks = 8 XCDs x 64)
//   -> each XCD's L2 serves exactly 2 (b,c) images (512KB) instead of all 16 (4MB).
// Kernel body byte-identical to R13.

using fp16x2 = __fp16 __attribute__((ext_vector_type(2)));
using half8  = __attribute__((ext_vector_type(8))) _Float16;
using f32x4  = __attribute__((ext_vector_type(4))) float;

constexpr int Bn = 2, Cn = 8, Kn = 2048, Hn = 128, Wn = 128;
constexpr int BC  = Bn * Cn;       // 16
constexpr int KPW = 16;            // k's per wave (one MFMA M-tile)
constexpr int WPB = 4;             // waves per block
constexpr int KPB = KPW * WPB;     // 64 k's per block
constexpr int NKS = Hn / 32;       // 4 K-steps over y
constexpr int SLOTS = Hn * Wn / 8; // 2048 half8 slots per component (32KB)

__device__ inline void cmul(float& ar, float& ai, float br, float bi) {
    float nr = fmaf(ar, br, -ai * bi);
    ai = fmaf(ar, bi, ai * br);
    ar = nr;
}
__device__ inline void csq(float& r, float& i) {
    float nr = fmaf(r, r, -i * i);
    i = 2.f * r * i;
    r = nr;
}

template<int OUT_COMPLEX>
__global__ __launch_bounds__(256, 2)
void nufft_mfma(const float* __restrict__ img_re, const float* __restrict__ img_im,
                const float* __restrict__ traj, float* __restrict__ out)
{
    __shared__ half8 re_lds[SLOTS];   // 32KB (full 128-row image, f16)
    __shared__ half8 im_lds[SLOTS];   // 32KB

    // XCD-aware swizzle: hardware round-robins bid%8 across XCDs; remap so each
    // XCD gets a contiguous 64-block chunk (= 2 full bc's sharing 2 images).
    const int bid  = (int)blockIdx.x;
    const int swz  = (bid & 7) * 64 + (bid >> 3);
    const int bc   = swz / (Kn / KPB);          // 0..15
    const int kt   = swz % (Kn / KPB);          // 0..31
    const int lane = threadIdx.x & 63;
    const int wave = threadIdx.x >> 6;          // 0..3
    const int xlo  = lane & 15;                 // n-lane (x within tile) / A k-row lane
    const int grp  = lane >> 4;                 // k-slot group (y-offset group)
    const int kbase = kt * KPB + wave * KPW;
    const size_t ibase = (size_t)bc * Hn * Wn;

    // ---- stage the FULL image, fp32 -> f16 (packed rtz) + XOR-swizzle:
    //      slot s holds (x = s>>4, y-chunk j = (s&15)^(x&7))  [R4-verified layout] ----
    #pragma unroll
    for (int i = 0; i < 8; ++i) {
        const int s  = i * 256 + (int)threadIdx.x;   // 0..2047
        const int x  = s >> 4;
        const int j  = (s & 15) ^ (x & 7);
        const float* gr = img_re + ibase + (size_t)x * Wn + j * 8;
        const float* gi = img_im + ibase + (size_t)x * Wn + j * 8;
        float4 a = ((const float4*)gr)[0], b = ((const float4*)gr)[1];
        float4 d = ((const float4*)gi)[0], e = ((const float4*)gi)[1];
        union { fp16x2 v2[4]; half8 v8; } ur, ui;
        ur.v2[0] = __builtin_amdgcn_cvt_pkrtz(a.x, a.y);
        ur.v2[1] = __builtin_amdgcn_cvt_pkrtz(a.z, a.w);
        ur.v2[2] = __builtin_amdgcn_cvt_pkrtz(b.x, b.y);
        ur.v2[3] = __builtin_amdgcn_cvt_pkrtz(b.z, b.w);
        ui.v2[0] = __builtin_amdgcn_cvt_pkrtz(d.x, d.y);
        ui.v2[1] = __builtin_amdgcn_cvt_pkrtz(d.z, d.w);
        ui.v2[2] = __builtin_amdgcn_cvt_pkrtz(e.x, e.y);
        ui.v2[3] = __builtin_amdgcn_cvt_pkrtz(e.z, e.w);
        re_lds[s] = ur.v8;
        im_lds[s] = ui.v8;
    }

    // ---- A (py) fragments, built ONCE (verified math), in the staging shadow ----
    const float om_y = traj[(size_t)(bc * 2 + 1) * Kn + (kbase + xlo)];
    float s, c;
    sincosf(om_y, &s, &c);
    const float syr = c, syi = -s;                    // exp(-i*om_y)
    sincosf(om_y * (float)(grp * 8 - 64), &s, &c);
    float pr = c, pi = -s;                            // phase at y = grp*8
    float t32r = syr, t32i = syi;                     // s_y^32
    #pragma unroll
    for (int q = 0; q < 5; ++q) csq(t32r, t32i);

    half8 Ar[NKS], Ai8[NKS], An[NKS];
    #pragma unroll
    for (int kk = 0; kk < NKS; ++kk) {
        float vr[8], vi[8];
        vr[0] = pr; vi[0] = pi;
        #pragma unroll
        for (int j = 1; j < 8; ++j) {
            float nr = fmaf(vr[j-1], syr, -vi[j-1] * syi);
            vi[j]    = fmaf(vr[j-1], syi,  vi[j-1] * syr);
            vr[j]    = nr;
        }
        #pragma unroll
        for (int j = 0; j < 8; ++j) {
            Ar[kk][j]  = (_Float16)vr[j];
            Ai8[kk][j] = (_Float16)vi[j];
            An[kk][j]  = (_Float16)(-vi[j]);
        }
        cmul(pr, pi, t32r, t32i);
    }

    // ---- epilogue px phase constants, hoisted (verified math) ----
    float eqr[4], eqi[4], etr[4], eti[4];
    #pragma unroll
    for (int r = 0; r < 4; ++r) {
        const int kr = kbase + grp * 4 + r;
        const float om_x = traj[(size_t)(bc * 2 + 0) * Kn + kr];
        sincosf(om_x, &s, &c);
        float t16r = c, t16i = -s;                    // exp(-i*om_x)
        sincosf(om_x * (float)(xlo - 64), &s, &c);
        eqr[r] = c; eqi[r] = -s;                      // phase at x = xlo
        #pragma unroll
        for (int q = 0; q < 4; ++q) csq(t16r, t16i);  // s_x^16
        etr[r] = t16r; eti[r] = t16i;
    }

    f32x4 accr[8], acci[8];
    #pragma unroll
    for (int a = 0; a < 8; ++a) { accr[a] = (f32x4)0.f; acci[a] = (f32x4)0.f; }

    __syncthreads();   // staging complete (the only barrier)

    // ---- MFMA core (R4-verified indexing over the full 8 x-tiles) ----
    for (int kk = 0; kk < NKS; ++kk) {
        const int jx = (kk * 4 + grp) ^ (xlo & 7);
        #pragma unroll
        for (int a = 0; a < 8; ++a) {
            const int slot = (a * 16 + xlo) * 16 + jx;
            half8 br = re_lds[slot];
            half8 bi = im_lds[slot];
            accr[a] = __builtin_amdgcn_mfma_f32_16x16x32_f16(Ar[kk],  br, accr[a], 0, 0, 0);
            accr[a] = __builtin_amdgcn_mfma_f32_16x16x32_f16(An[kk],  bi, accr[a], 0, 0, 0);
            acci[a] = __builtin_amdgcn_mfma_f32_16x16x32_f16(Ar[kk],  bi, acci[a], 0, 0, 0);
            acci[a] = __builtin_amdgcn_mfma_f32_16x16x32_f16(Ai8[kk], br, acci[a], 0, 0, 0);
        }
    }

    // ---- epilogue (verified): out[k] = sum_x tmp[k,x]*px[k,x] ----
    float outr[4], outi[4];
    #pragma unroll
    for (int r = 0; r < 4; ++r) {
        float qr = eqr[r], qi = eqi[r];
        const float t16r = etr[r], t16i = eti[r];
        float orr = 0.f, oii = 0.f;
        #pragma unroll
        for (int a = 0; a < 8; ++a) {
            const float tre = accr[a][r], tim = acci[a][r];
            orr = fmaf(tre, qr, orr); orr = fmaf(-tim, qi, orr);
            oii = fmaf(tre, qi, oii); oii = fmaf( tim, qr, oii);
            cmul(qr, qi, t16r, t16i);
        }
        #pragma unroll
        for (int m = 1; m < 16; m <<= 1) {
            orr += __shfl_xor(orr, m, 64);
            oii += __shfl_xor(oii, m, 64);
        }
        outr[r] = orr; outi[r] = oii;
    }

    if (xlo == 0) {
        #pragma unroll
        for (int r = 0; r < 4; ++r) {
            const int kr = kbase + grp * 4 + r;
            if (OUT_COMPLEX) {
                out[((size_t)bc * Kn + kr) * 2 + 0] = outr[r];
                out[((size_t)bc * Kn + kr) * 2 + 1] = outi[r];
            } else {
                out[(size_t)bc * Kn + kr] = outr[r];
            }
        }
    }
}

extern "C" void kernel_launch(void* const* d_in, const int* in_sizes, int n_in,
                              void* d_out, int out_size, void* d_ws, size_t ws_size,
                              hipStream_t stream) {
    const float* img_re = (const float*)d_in[0];
    const float* img_im = (const float*)d_in[1];
    const float* traj   = (const float*)d_in[2];
    float* out = (float*)d_out;

    dim3 grid(BC * (Kn / KPB));   // 512 blocks
    dim3 block(WPB * 64);         // 256 threads
    const bool cplx = (out_size == BC * Kn * 2);

    if (cplx) hipLaunchKernelGGL((nufft_mfma<1>), grid, block, 0, stream, img_re, img_im, traj, out);
    else      hipLaunchKernelGGL((nufft_mfma<0>), grid, block, 0, stream, img_re, img_im, traj, out);
}

// Round 15
// 12.557 us; speedup vs baseline: 1.0194x; 1.0194x over previous
//
#include <hip/hip_runtime.h>
#include <math.h>

// NUFFT type-2 exact NUDFT via MFMA, LDS-resident B.
// R15 = R13 (verified, 12.69us) with 8 waves/block (KPB=128, grid=256):
// staging work per thread halves (4 slot-stores) and chip-wide staged L2 reads
// halve; every wave runs the byte-identical R13 program (own 16 k's, all 8
// x-tiles, full y; read-only shared LDS image; NO cross-wave communication).
//   tmp[k,x] = sum_y py[k,y]*img[x,y]  (f16 MFMA, fp32 acc)
//   out[k]   = sum_x tmp[k,x]*px[k,x]  (VALU epilogue, 16-lane butterfly, direct store)

using fp16x2 = __fp16 __attribute__((ext_vector_type(2)));
using half8  = __attribute__((ext_vector_type(8))) _Float16;
using f32x4  = __attribute__((ext_vector_type(4))) float;

constexpr int Bn = 2, Cn = 8, Kn = 2048, Hn = 128, Wn = 128;
constexpr int BC  = Bn * Cn;       // 16
constexpr int KPW = 16;            // k's per wave (one MFMA M-tile)
constexpr int WPB = 8;             // waves per block
constexpr int KPB = KPW * WPB;     // 128 k's per block
constexpr int NKS = Hn / 32;       // 4 K-steps over y
constexpr int SLOTS = Hn * Wn / 8; // 2048 half8 slots per component (32KB)

__device__ inline void cmul(float& ar, float& ai, float br, float bi) {
    float nr = fmaf(ar, br, -ai * bi);
    ai = fmaf(ar, bi, ai * br);
    ar = nr;
}
__device__ inline void csq(float& r, float& i) {
    float nr = fmaf(r, r, -i * i);
    i = 2.f * r * i;
    r = nr;
}

template<int OUT_COMPLEX>
__global__ __launch_bounds__(512, 2)
void nufft_mfma(const float* __restrict__ img_re, const float* __restrict__ img_im,
                const float* __restrict__ traj, float* __restrict__ out)
{
    __shared__ half8 re_lds[SLOTS];   // 32KB (full 128-row image, f16)
    __shared__ half8 im_lds[SLOTS];   // 32KB

    const int bc   = blockIdx.x / (Kn / KPB);   // 0..15
    const int kt   = blockIdx.x % (Kn / KPB);   // 0..15
    const int lane = threadIdx.x & 63;
    const int wave = threadIdx.x >> 6;          // 0..7
    const int xlo  = lane & 15;                 // n-lane (x within tile) / A k-row lane
    const int grp  = lane >> 4;                 // k-slot group (y-offset group)
    const int kbase = kt * KPB + wave * KPW;
    const size_t ibase = (size_t)bc * Hn * Wn;

    // ---- stage the FULL image, fp32 -> f16 (packed rtz) + XOR-swizzle:
    //      slot s holds (x = s>>4, y-chunk j = (s&15)^(x&7))  [R4-verified layout] ----
    #pragma unroll
    for (int i = 0; i < 4; ++i) {
        const int s  = i * 512 + (int)threadIdx.x;   // 0..2047
        const int x  = s >> 4;
        const int j  = (s & 15) ^ (x & 7);
        const float* gr = img_re + ibase + (size_t)x * Wn + j * 8;
        const float* gi = img_im + ibase + (size_t)x * Wn + j * 8;
        float4 a = ((const float4*)gr)[0], b = ((const float4*)gr)[1];
        float4 d = ((const float4*)gi)[0], e = ((const float4*)gi)[1];
        union { fp16x2 v2[4]; half8 v8; } ur, ui;
        ur.v2[0] = __builtin_amdgcn_cvt_pkrtz(a.x, a.y);
        ur.v2[1] = __builtin_amdgcn_cvt_pkrtz(a.z, a.w);
        ur.v2[2] = __builtin_amdgcn_cvt_pkrtz(b.x, b.y);
        ur.v2[3] = __builtin_amdgcn_cvt_pkrtz(b.z, b.w);
        ui.v2[0] = __builtin_amdgcn_cvt_pkrtz(d.x, d.y);
        ui.v2[1] = __builtin_amdgcn_cvt_pkrtz(d.z, d.w);
        ui.v2[2] = __builtin_amdgcn_cvt_pkrtz(e.x, e.y);
        ui.v2[3] = __builtin_amdgcn_cvt_pkrtz(e.z, e.w);
        re_lds[s] = ur.v8;
        im_lds[s] = ui.v8;
    }

    // ---- A (py) fragments, built ONCE (verified math), in the staging shadow ----
    const float om_y = traj[(size_t)(bc * 2 + 1) * Kn + (kbase + xlo)];
    float s, c;
    sincosf(om_y, &s, &c);
    const float syr = c, syi = -s;                    // exp(-i*om_y)
    sincosf(om_y * (float)(grp * 8 - 64), &s, &c);
    float pr = c, pi = -s;                            // phase at y = grp*8
    float t32r = syr, t32i = syi;                     // s_y^32
    #pragma unroll
    for (int q = 0; q < 5; ++q) csq(t32r, t32i);

    half8 Ar[NKS], Ai8[NKS], An[NKS];
    #pragma unroll
    for (int kk = 0; kk < NKS; ++kk) {
        float vr[8], vi[8];
        vr[0] = pr; vi[0] = pi;
        #pragma unroll
        for (int j = 1; j < 8; ++j) {
            float nr = fmaf(vr[j-1], syr, -vi[j-1] * syi);
            vi[j]    = fmaf(vr[j-1], syi,  vi[j-1] * syr);
            vr[j]    = nr;
        }
        #pragma unroll
        for (int j = 0; j < 8; ++j) {
            Ar[kk][j]  = (_Float16)vr[j];
            Ai8[kk][j] = (_Float16)vi[j];
            An[kk][j]  = (_Float16)(-vi[j]);
        }
        cmul(pr, pi, t32r, t32i);
    }

    // ---- epilogue px phase constants, hoisted (verified math) ----
    float eqr[4], eqi[4], etr[4], eti[4];
    #pragma unroll
    for (int r = 0; r < 4; ++r) {
        const int kr = kbase + grp * 4 + r;
        const float om_x = traj[(size_t)(bc * 2 + 0) * Kn + kr];
        sincosf(om_x, &s, &c);
        float t16r = c, t16i = -s;                    // exp(-i*om_x)
        sincosf(om_x * (float)(xlo - 64), &s, &c);
        eqr[r] = c; eqi[r] = -s;                      // phase at x = xlo
        #pragma unroll
        for (int q = 0; q < 4; ++q) csq(t16r, t16i);  // s_x^16
        etr[r] = t16r; eti[r] = t16i;
    }

    f32x4 accr[8], acci[8];
    #pragma unroll
    for (int a = 0; a < 8; ++a) { accr[a] = (f32x4)0.f; acci[a] = (f32x4)0.f; }

    __syncthreads();   // staging complete (the only barrier)

    // ---- MFMA core (R4-verified indexing over the full 8 x-tiles) ----
    for (int kk = 0; kk < NKS; ++kk) {
        const int jx = (kk * 4 + grp) ^ (xlo & 7);
        #pragma unroll
        for (int a = 0; a < 8; ++a) {
            const int slot = (a * 16 + xlo) * 16 + jx;
            half8 br = re_lds[slot];
            half8 bi = im_lds[slot];
            accr[a] = __builtin_amdgcn_mfma_f32_16x16x32_f16(Ar[kk],  br, accr[a], 0, 0, 0);
            accr[a] = __builtin_amdgcn_mfma_f32_16x16x32_f16(An[kk],  bi, accr[a], 0, 0, 0);
            acci[a] = __builtin_amdgcn_mfma_f32_16x16x32_f16(Ar[kk],  bi, acci[a], 0, 0, 0);
            acci[a] = __builtin_amdgcn_mfma_f32_16x16x32_f16(Ai8[kk], br, acci[a], 0, 0, 0);
        }
    }

    // ---- epilogue (verified): out[k] = sum_x tmp[k,x]*px[k,x] ----
    float outr[4], outi[4];
    #pragma unroll
    for (int r = 0; r < 4; ++r) {
        float qr = eqr[r], qi = eqi[r];
        const float t16r = etr[r], t16i = eti[r];
        float orr = 0.f, oii = 0.f;
        #pragma unroll
        for (int a = 0; a < 8; ++a) {
            const float tre = accr[a][r], tim = acci[a][r];
            orr = fmaf(tre, qr, orr); orr = fmaf(-tim, qi, orr);
            oii = fmaf(tre, qi, oii); oii = fmaf( tim, qr, oii);
            cmul(qr, qi, t16r, t16i);
        }
        #pragma unroll
        for (int m = 1; m < 16; m <<= 1) {
            orr += __shfl_xor(orr, m, 64);
            oii += __shfl_xor(oii, m, 64);
        }
        outr[r] = orr; outi[r] = oii;
    }

    if (xlo == 0) {
        #pragma unroll
        for (int r = 0; r < 4; ++r) {
            const int kr = kbase + grp * 4 + r;
            if (OUT_COMPLEX) {
                out[((size_t)bc * Kn + kr) * 2 + 0] = outr[r];
                out[((size_t)bc * Kn + kr) * 2 + 1] = outi[r];
            } else {
                out[(size_t)bc * Kn + kr] = outr[r];
            }
        }
    }
}

extern "C" void kernel_launch(void* const* d_in, const int* in_sizes, int n_in,
                              void* d_out, int out_size, void* d_ws, size_t ws_size,
                              hipStream_t stream) {
    const float* img_re = (const float*)d_in[0];
    const float* img_im = (const float*)d_in[1];
    const float* traj   = (const float*)d_in[2];
    float* out = (float*)d_out;

    dim3 grid(BC * (Kn / KPB));   // 256 blocks
    dim3 block(WPB * 64);         // 512 threads = 8 waves
    const bool cplx = (out_size == BC * Kn * 2);

    if (cplx) hipLaunchKernelGGL((nufft_mfma<1>), grid, block, 0, stream, img_re, img_im, traj, out);
    else      hipLaunchKernelGGL((nufft_mfma<0>), grid, block, 0, stream, img_re, img_im, traj, out);
}